// Round 4
// baseline (1218.406 us; speedup 1.0000x reference)
//
#include <hip/hip_runtime.h>
#include <hip/hip_bf16.h>

typedef unsigned short u16;
typedef __attribute__((ext_vector_type(8))) short bf16x8;
typedef __attribute__((ext_vector_type(4))) float f32x4;

#define NE 500000
#define NBLOCKS ((NE + 63) / 64)

// ---------------- d_ws layout ----------------
#define WE0_U 0u        // [128][256]
#define WE1_U 32768u    // [128][128]
#define WE2_U 49152u    // [128][128]
#define WE3_U 65536u    // [16][128]  (rows 10..15 zero)
#define WD0_U 67584u    // [128][32]  (k 5..31 zero)
#define WD1_U 71680u    // [128][128]
#define WD2_U 88064u    // [128][128]
#define WD3_U 104448u   // [256][128]
#define BIAS_F 68608u   // float index base (byte 274432/4)
#define BE0_F 0
#define BE1_F 128
#define BE2_F 256
#define BE3_F 384
#define BD0_F 400
#define BD1_F 528
#define BD2_F 656
#define BD3_F 784
#define NBIAS 1040
#define ACC_BYTE 278592u  // double[2]: rl_sum, kl_sum

__device__ __forceinline__ u16 f2bf(float f) {
  __hip_bfloat16 h = __float2bfloat16(f);
  u16 u;
  __builtin_memcpy(&u, &h, 2);
  return u;
}

// ---------------- prep: transpose weights to bf16 [N][K], copy biases, zero accum ----------------
__global__ void prep_kernel(const float* __restrict__ eW0, const float* __restrict__ eb0,
                            const float* __restrict__ eW1, const float* __restrict__ eb1,
                            const float* __restrict__ eW2, const float* __restrict__ eb2,
                            const float* __restrict__ eW3, const float* __restrict__ eb3,
                            const float* __restrict__ dW0, const float* __restrict__ db0,
                            const float* __restrict__ dW1, const float* __restrict__ db1,
                            const float* __restrict__ dW2, const float* __restrict__ db2,
                            const float* __restrict__ dW3, const float* __restrict__ db3,
                            u16* __restrict__ wsu) {
  int t = blockIdx.x * 256 + threadIdx.x;
  float* wsf = (float*)wsu;
  if (t < 32768) {
    int n = t >> 8, k = t & 255;
    wsu[WE0_U + n * 256 + k] = f2bf(eW0[k * 128 + n]);
  } else if (t < 49152) {
    int i = t - 32768, n = i >> 7, k = i & 127;
    wsu[WE1_U + n * 128 + k] = f2bf(eW1[k * 128 + n]);
  } else if (t < 65536) {
    int i = t - 49152, n = i >> 7, k = i & 127;
    wsu[WE2_U + n * 128 + k] = f2bf(eW2[k * 128 + n]);
  } else if (t < 67584) {
    int i = t - 65536, n = i >> 7, k = i & 127;
    wsu[WE3_U + n * 128 + k] = f2bf(n < 10 ? eW3[k * 10 + n] : 0.f);
  } else if (t < 71680) {
    int i = t - 67584, n = i >> 5, k = i & 31;
    wsu[WD0_U + n * 32 + k] = f2bf(k < 5 ? dW0[k * 128 + n] : 0.f);
  } else if (t < 88064) {
    int i = t - 71680, n = i >> 7, k = i & 127;
    wsu[WD1_U + n * 128 + k] = f2bf(dW1[k * 128 + n]);
  } else if (t < 104448) {
    int i = t - 88064, n = i >> 7, k = i & 127;
    wsu[WD2_U + n * 128 + k] = f2bf(dW2[k * 128 + n]);
  } else if (t < 137216) {
    int i = t - 104448, n = i >> 7, k = i & 127;
    wsu[WD3_U + n * 128 + k] = f2bf(dW3[k * 256 + n]);
  } else if (t < 137216 + NBIAS) {
    int i = t - 137216;
    float v;
    if (i < 128) v = eb0[i];
    else if (i < 256) v = eb1[i - 128];
    else if (i < 384) v = eb2[i - 256];
    else if (i < 400) v = (i - 384 < 10) ? eb3[i - 384] : 0.f;
    else if (i < 528) v = db0[i - 400];
    else if (i < 656) v = db1[i - 528];
    else if (i < 784) v = db2[i - 656];
    else v = db3[i - 784];
    wsf[BIAS_F + i] = v;
  } else if (t < 137216 + NBIAS + 2) {
    ((double*)((char*)wsu + ACC_BYTE))[t - 137216 - NBIAS] = 0.0;
  }
}

// ---------------- helpers ----------------
// LDS activation tiles: [64 rows][128 bf16], XOR-swizzled byte ^= (row&7)<<4
__device__ __forceinline__ bf16x8 ldA(const u16* buf, int row, int k) {
  int byte = (row * 256 + k * 2) ^ ((row & 7) << 4);
  return *(const bf16x8*)((const char*)buf + byte);
}

__device__ __forceinline__ void init_acc(f32x4 acc[8], const float* __restrict__ bias, int j) {
  #pragma unroll
  for (int n = 0; n < 8; ++n) {
    float b = bias[n * 16 + j];
    f32x4 v = {b, b, b, b};
    acc[n] = v;
  }
}

// wave computes 16 rows (rw..rw+15) x 128 cols over K=128
template<int LDW>
__device__ __forceinline__ void gemm_acc(const u16* __restrict__ inb, const u16* __restrict__ Wt,
                                         int k0, f32x4 acc[8], int rw, int g, int j) {
  #pragma unroll
  for (int kk = 0; kk < 4; ++kk) {
    int k = kk * 32 + g * 8;
    bf16x8 a0 = ldA(inb, rw + j, k);
    #pragma unroll
    for (int n = 0; n < 8; ++n) {
      bf16x8 b = *(const bf16x8*)(Wt + (n * 16 + j) * LDW + k0 + k);
      acc[n] = __builtin_amdgcn_mfma_f32_16x16x32_bf16(a0, b, acc[n], 0, 0, 0);
    }
  }
}

// C layout: col = lane&15, row = (lane>>4)*4 + reg
__device__ __forceinline__ void store_act(const f32x4 acc[8], u16* outb, int rw, int g, int j,
                                          bool relu) {
  #pragma unroll
  for (int n = 0; n < 8; ++n)
    #pragma unroll
    for (int r = 0; r < 4; ++r) {
      float v = acc[n][r];
      if (relu) v = fmaxf(v, 0.f);
      int row = rw + g * 4 + r;
      int c = n * 16 + j;
      int byte = (row * 256 + c * 2) ^ ((row & 7) << 4);
      *(u16*)((char*)outb + byte) = f2bf(v);
    }
}

// gather 64 node rows (fp32) -> bf16 swizzled LDS tile; 4 threads/row
__device__ __forceinline__ void stage(const float* __restrict__ x, const int* __restrict__ idx,
                                      int e0, u16* buf, int tid) {
  int rl = tid >> 2;   // 0..63
  int sub = tid & 3;   // 32-float segment
  int e = e0 + rl;
  if (e >= NE) e = NE - 1;
  int node = idx[e];
  const f32x4* src = (const f32x4*)(x + (size_t)node * 128 + sub * 32);
  #pragma unroll
  for (int c = 0; c < 4; ++c) {
    f32x4 v0 = src[c * 2];
    f32x4 v1 = src[c * 2 + 1];
    bf16x8 o;
    o[0] = (short)f2bf(v0[0]); o[1] = (short)f2bf(v0[1]);
    o[2] = (short)f2bf(v0[2]); o[3] = (short)f2bf(v0[3]);
    o[4] = (short)f2bf(v1[0]); o[5] = (short)f2bf(v1[1]);
    o[6] = (short)f2bf(v1[2]); o[7] = (short)f2bf(v1[3]);
    int col = sub * 32 + c * 8;
    int byte = (rl * 256 + col * 2) ^ ((rl & 7) << 4);
    *(bf16x8*)((char*)buf + byte) = o;
  }
}

// ---------------- main fused kernel: 1 block = 64 edges, 4 waves x 16 rows ----------------
__global__ __launch_bounds__(256, 4) void vae_kernel(
    const float* __restrict__ x, const int* __restrict__ rowi, const int* __restrict__ coli,
    const float* __restrict__ eps, const u16* __restrict__ wsu, double* __restrict__ accg,
    float* __restrict__ out) {
  __shared__ __align__(16) u16 bufA[64 * 128];
  __shared__ __align__(16) u16 bufB[64 * 128];
  __shared__ __align__(16) u16 zbuf[64 * 32];   // [row][32], k 5..31 zero
  __shared__ float redr[4], redk[4];

  const float* wsf = (const float*)wsu;
  const int tid = threadIdx.x;
  const int lane = tid & 63;
  const int wave = tid >> 6;
  const int g = lane >> 4;
  const int j = lane & 15;
  const int rw = wave * 16;
  const int e0 = blockIdx.x * 64;

  for (int i = tid; i < 64 * 32; i += 256) zbuf[i] = 0;

  float kl_part = 0.f, rl_part = 0.f;
  f32x4 acc[8];

  // ---- stage both pair halves up-front (overlapped gather chains) ----
  stage(x, rowi, e0, bufA, tid);
  stage(x, coli, e0, bufB, tid);
  __syncthreads();

  // ---- enc0: [64x256] @ eW0 (K halves in A and B) ----
  init_acc(acc, wsf + BIAS_F + BE0_F, j);
  gemm_acc<256>(bufA, wsu + WE0_U, 0, acc, rw, g, j);
  gemm_acc<256>(bufB, wsu + WE0_U, 128, acc, rw, g, j);
  __syncthreads();                     // all reads of A,B complete
  store_act(acc, bufA, rw, g, j, true);
  __syncthreads();

  // ---- enc1: A -> B ----
  init_acc(acc, wsf + BIAS_F + BE1_F, j);
  gemm_acc<128>(bufA, wsu + WE1_U, 0, acc, rw, g, j);
  store_act(acc, bufB, rw, g, j, true);
  __syncthreads();

  // ---- enc2: B -> A ----
  init_acc(acc, wsf + BIAS_F + BE2_F, j);
  gemm_acc<128>(bufB, wsu + WE2_U, 0, acc, rw, g, j);
  store_act(acc, bufA, rw, g, j, true);
  __syncthreads();

  // ---- enc3: A -> mu/logvar (N=16: cols 0..4 mu, 5..9 logvar) ----
  f32x4 a3;
  {
    float b3 = wsf[BIAS_F + BE3_F + j];
    f32x4 v = {b3, b3, b3, b3};
    a3 = v;
    #pragma unroll
    for (int kk = 0; kk < 4; ++kk) {
      int k = kk * 32 + g * 8;
      bf16x8 q0 = ldA(bufA, rw + j, k);
      bf16x8 b = *(const bf16x8*)(wsu + WE3_U + j * 128 + k);
      a3 = __builtin_amdgcn_mfma_f32_16x16x32_bf16(q0, b, a3, 0, 0, 0);
    }
  }

  // ---- reparameterization + KL ----
  {
    int src = g * 16 + ((j + 5) & 15);
    #pragma unroll
    for (int r = 0; r < 4; ++r) {
      float muv = a3[r];
      float lvv = __shfl(a3[r], src, 64);
      if (j < 5) {
        int row = rw + g * 4 + r;
        int e = e0 + row;
        int ec = e < NE ? e : NE - 1;
        float stdv = __expf(0.5f * lvv);
        float zv = muv + eps[(size_t)ec * 5 + j] * stdv;
        zbuf[row * 32 + j] = f2bf(zv);
        if (e < NE) kl_part += 1.0f + lvv - muv * muv - __expf(lvv);
      }
    }
  }

  // hoist loss node indices (independent loads, hide latency under decoder)
  int rn[4], cn[4];
  #pragma unroll
  for (int r = 0; r < 4; ++r) {
    int e = e0 + rw + g * 4 + r;
    int ec = e < NE ? e : NE - 1;
    rn[r] = rowi[ec];
    cn[r] = coli[ec];
  }
  __syncthreads();   // zbuf visible; enc3 reads of A done

  // ---- dec0: z[64x5 pad 32] @ dW0 -> B ----
  init_acc(acc, wsf + BIAS_F + BD0_F, j);
  {
    int k = g * 8;
    bf16x8 q0 = *(const bf16x8*)(zbuf + (rw + j) * 32 + k);
    #pragma unroll
    for (int n = 0; n < 8; ++n) {
      bf16x8 b = *(const bf16x8*)(wsu + WD0_U + (n * 16 + j) * 32 + k);
      acc[n] = __builtin_amdgcn_mfma_f32_16x16x32_bf16(q0, b, acc[n], 0, 0, 0);
    }
  }
  store_act(acc, bufB, rw, g, j, true);
  __syncthreads();

  // ---- dec1: B -> A ----
  init_acc(acc, wsf + BIAS_F + BD1_F, j);
  gemm_acc<128>(bufB, wsu + WD1_U, 0, acc, rw, g, j);
  store_act(acc, bufA, rw, g, j, true);
  __syncthreads();

  // ---- dec2: A -> B ----
  init_acc(acc, wsf + BIAS_F + BD2_F, j);
  gemm_acc<128>(bufA, wsu + WD2_U, 0, acc, rw, g, j);
  store_act(acc, bufB, rw, g, j, true);
  __syncthreads();

  // ---- dec3 (N=256 in two halves) fused with recon loss ----
  float rlsq[4] = {0.f, 0.f, 0.f, 0.f};
  #pragma unroll
  for (int nh = 0; nh < 2; ++nh) {
    init_acc(acc, wsf + BIAS_F + BD3_F + nh * 128, j);
    #pragma unroll
    for (int kk = 0; kk < 4; ++kk) {
      int k = kk * 32 + g * 8;
      bf16x8 q0 = ldA(bufB, rw + j, k);
      #pragma unroll
      for (int n = 0; n < 8; ++n) {
        bf16x8 b = *(const bf16x8*)(wsu + WD3_U + (nh * 128 + n * 16 + j) * 128 + k);
        acc[n] = __builtin_amdgcn_mfma_f32_16x16x32_bf16(q0, b, acc[n], 0, 0, 0);
      }
    }
    #pragma unroll
    for (int n = 0; n < 8; ++n)
      #pragma unroll
      for (int r = 0; r < 4; ++r) {
        int c = nh * 128 + n * 16 + j;
        int node = (nh == 0) ? rn[r] : cn[r];
        float pv = x[(size_t)node * 128 + (c & 127)];
        float d = acc[n][r] - pv;
        rlsq[r] += d * d;
      }
  }

  // per-row reduce over 16 col-lanes -> rl, affinity
  #pragma unroll
  for (int r = 0; r < 4; ++r) {
    float v = rlsq[r];
    v += __shfl_xor(v, 1);
    v += __shfl_xor(v, 2);
    v += __shfl_xor(v, 4);
    v += __shfl_xor(v, 8);
    if (j == 0) {
      int e = e0 + rw + g * 4 + r;
      if (e < NE) {
        float rl = sqrtf(v);
        out[e] = 1.0f / (1.0f + 3.5f * rl);
        rl_part += rl;
      }
    }
  }

  // ---- block reduction + global double atomics ----
  float kv = kl_part, rv = rl_part;
  #pragma unroll
  for (int msk = 1; msk < 64; msk <<= 1) {
    kv += __shfl_xor(kv, msk);
    rv += __shfl_xor(rv, msk);
  }
  if (lane == 0) {
    redk[wave] = kv;
    redr[wave] = rv;
  }
  __syncthreads();
  if (tid == 0) {
    atomicAdd(&accg[0], (double)(redr[0] + redr[1] + redr[2] + redr[3]));
    atomicAdd(&accg[1], (double)(redk[0] + redk[1] + redk[2] + redk[3]));
  }
}

// ---------------- finalize ----------------
__global__ void fin_kernel(const double* __restrict__ accg, float* __restrict__ out) {
  if (threadIdx.x == 0) {
    out[NE] = (float)(accg[0] / (double)NE);
    out[NE + 1] = (float)(accg[1] * (-0.5 * 10.0 / ((double)NE * 5.0)));
  }
}

extern "C" void kernel_launch(void* const* d_in, const int* in_sizes, int n_in,
                              void* d_out, int out_size, void* d_ws, size_t ws_size,
                              hipStream_t stream) {
  (void)in_sizes; (void)n_in; (void)out_size; (void)ws_size;
  const float* x   = (const float*)d_in[0];
  const int*   row = (const int*)d_in[1];
  const int*   col = (const int*)d_in[2];
  const float* eps = (const float*)d_in[3];
  u16* wsu = (u16*)d_ws;
  double* accg = (double*)((char*)d_ws + ACC_BYTE);
  float* out = (float*)d_out;

  prep_kernel<<<541, 256, 0, stream>>>(
      (const float*)d_in[4],  (const float*)d_in[5],  (const float*)d_in[6],  (const float*)d_in[7],
      (const float*)d_in[8],  (const float*)d_in[9],  (const float*)d_in[10], (const float*)d_in[11],
      (const float*)d_in[12], (const float*)d_in[13], (const float*)d_in[14], (const float*)d_in[15],
      (const float*)d_in[16], (const float*)d_in[17], (const float*)d_in[18], (const float*)d_in[19],
      wsu);
  vae_kernel<<<NBLOCKS, 256, 0, stream>>>(x, row, col, eps, wsu, accg, out);
  fin_kernel<<<1, 64, 0, stream>>>(accg, out);
}